// Round 10
// baseline (585.376 us; speedup 1.0000x reference)
//
#include <hip/hip_runtime.h>
#include <hip/hip_bf16.h>

#define N_NODES 50000
#define N_EDGES 800000
#define N_GRAPHS 64
#define SCAN_B 196   // ceil(N_NODES/256); also = number of dst bins (256 nodes each)
#define FT_B   3125  // N_NODES/16
#define GAP_B  512   // 64 graphs * 8 parts
#define SHARDS 4
#define BCAP   1408  // per-shard bin capacity (mean 1020, sigma ~32 -> 12 sigma)
#define ZINTS  50832 // ints to zero: deg(padded 50048) + cnt(784)

typedef unsigned short u16;
typedef unsigned char u8;
typedef short s16x8 __attribute__((ext_vector_type(8)));
typedef float f32x4 __attribute__((ext_vector_type(4)));
typedef float f32x2 __attribute__((ext_vector_type(2)));

__device__ __forceinline__ float bf2f(u16 u) {
    union { unsigned int i; float f; } v; v.i = ((unsigned int)u) << 16; return v.f;
}
__device__ __forceinline__ u16 f2bf(float f) {
    union { float f; unsigned int i; } v; v.f = f;
    unsigned int i = v.i;
    unsigned int r = i + 0x7fffu + ((i >> 16) & 1u);
    return (u16)(r >> 16);
}
__device__ __forceinline__ float asfloat(unsigned int u) {
    union { unsigned int i; float f; } v; v.i = u; return v.f;
}

// ---------------- fused: zero (deg|cnt) + (x = concat*centrality, gate logit) ----------------
__global__ __launch_bounds__(256) void k_init(const float* __restrict__ nf, const float* __restrict__ nm,
                                              const float* __restrict__ cent, const float* __restrict__ Wg,
                                              const float* __restrict__ bg,
                                              u16* __restrict__ x, float* __restrict__ g,
                                              int* __restrict__ zbase) {
    int b = blockIdx.x;
    if (b < SCAN_B) {                 // zero deg + bin counters (contiguous)
        int i = b * 256 + threadIdx.x;
        if (i < ZINTS) zbase[i] = 0;
        i += SCAN_B * 256;
        if (i < ZINTS) zbase[i] = 0;
        return;
    }
    b -= SCAN_B;
    int node = b * 4 + (threadIdx.x >> 6);
    int lane = threadIdx.x & 63;
    float v = (lane < 48) ? nf[(size_t)node * 48 + lane] : nm[(size_t)node * 16 + lane - 48];
    float xf = v * cent[node];
    x[(size_t)node * 64 + lane] = f2bf(xf);
    float p = xf * Wg[lane];
#pragma unroll
    for (int mm = 1; mm < 64; mm <<= 1) p += __shfl_xor(p, mm);
    if (lane == 0) g[node] = p + bg[0];
}

// ---------------- pass A: deg histogram + deposit edges into dst bins (sharded cursors) ----------------
__global__ __launch_bounds__(256) void k_bin(const int* __restrict__ src, const int* __restrict__ dst,
                                             const float* __restrict__ ew,
                                             int* __restrict__ deg, int* __restrict__ cnt,
                                             int2* __restrict__ binse, u8* __restrict__ dstlo) {
    int e = blockIdx.x * 256 + threadIdx.x;
    if (e >= N_EDGES) return;
    int d = dst[e];
    atomicAdd(&deg[d], 1);
    int bin = d >> 8;
    int sh = bin * SHARDS + (threadIdx.x & (SHARDS - 1));
    int pos = atomicAdd(&cnt[sh], 1);
    if (pos < BCAP) {
        size_t base = (size_t)sh * BCAP + pos;
        binse[base] = make_int2(src[e], __float_as_int(ew[e]));
        dstlo[base] = (u8)(d & 255);
    }
}

__global__ __launch_bounds__(256) void k_scanA(const int* __restrict__ deg,
                                               int* __restrict__ rowptr, int* __restrict__ bsum) {
    int b = blockIdx.x, t = threadIdx.x;
    int i = b * 256 + t;
    int v = (i < N_NODES) ? deg[i] : 0;
    int orig = v;
    int lane = t & 63, w = t >> 6;
#pragma unroll
    for (int d = 1; d < 64; d <<= 1) {
        int u = __shfl_up(v, d);
        if (lane >= d) v += u;
    }
    __shared__ int wsum[4];
    if (lane == 63) wsum[w] = v;
    __syncthreads();
    int add = 0;
    for (int k = 0; k < w; k++) add += wsum[k];
    v += add;
    if (i < N_NODES) rowptr[i] = v - orig;   // local exclusive
    if (t == 255) bsum[b] = v;
}

// fused: block 0 = scan of block sums; blocks 1..12 = W transpose (independent)
__global__ __launch_bounds__(256) void k_scanBprep(const int* __restrict__ bsum, int* __restrict__ boff,
                                                   const float* __restrict__ W1, const float* __restrict__ W2,
                                                   const float* __restrict__ W3, u16* __restrict__ Wt) {
    __shared__ float tile[64][65];
    __shared__ int wsum[4];
    if (blockIdx.x == 0) {
        int t = threadIdx.x;
        int v = (t < SCAN_B) ? bsum[t] : 0;
        int orig = v;
        int lane = t & 63, w = t >> 6;
#pragma unroll
        for (int d = 1; d < 64; d <<= 1) {
            int u = __shfl_up(v, d);
            if (lane >= d) v += u;
        }
        if (lane == 63) wsum[w] = v;
        __syncthreads();
        int add = 0;
        for (int k = 0; k < w; k++) add += wsum[k];
        v += add;
        if (t < SCAN_B) boff[t] = v - orig;
        return;
    }
    int bb = blockIdx.x - 1;
    int l = bb >> 2, ti = bb & 3;
    const float* W = (l == 0) ? W1 : (l == 1) ? W2 : W3;
    u16* o = Wt + (size_t)l * 64 * 256;
    int t = threadIdx.x;
    for (int i = t; i < 64 * 64; i += 256) {
        int d = i >> 6, c = i & 63;
        tile[d][c] = W[d * 256 + ti * 64 + c];
    }
    __syncthreads();
    for (int i = t; i < 64 * 64; i += 256) {
        int c = i >> 6, d = i & 63;
        o[(size_t)(ti * 64 + c) * 64 + d] = f2bf(tile[d][c]);
    }
}

// ---------------- pass C: finalize rowptr (local + boff) + LDS-cursor scatter per bin ----------------
__global__ __launch_bounds__(256) void k_csr(int* __restrict__ rowptr, const int* __restrict__ deg,
                                             const int* __restrict__ boff, const int* __restrict__ cnt,
                                             const int2* __restrict__ binse, const u8* __restrict__ dstlo,
                                             int2* __restrict__ csr_se) {
    int bin = blockIdx.x, t = threadIdx.x;
    __shared__ int cur[256];
    int node = bin * 256 + t;
    if (node < N_NODES) {
        int val = rowptr[node] + boff[bin];
        rowptr[node] = val;
        cur[t] = val;
        if (node == N_NODES - 1) rowptr[N_NODES] = val + deg[node];
    }
    __syncthreads();
#pragma unroll
    for (int s = 0; s < SHARDS; s++) {
        int g = bin * SHARDS + s;
        int count = cnt[g]; if (count > BCAP) count = BCAP;
        const int2* se = binse + (size_t)g * BCAP;
        const u8* dl = dstlo + (size_t)g * BCAP;
        for (int i = t; i < count; i += 256) {
            int2 e = se[i];
            int pos = atomicAdd(&cur[dl[i]], 1);
            csr_se[pos] = e;
        }
    }
}

// ---------------- GAP partial (device fn): 8 parts/graph, no-max exp ----------------
__device__ __forceinline__ void gap_part(int pb, const u16* __restrict__ x, const float* __restrict__ g,
                                         const int* __restrict__ gid,
                                         float* __restrict__ pnum, float* __restrict__ pden) {
    int part = pb & 7, b = pb >> 3;
    int t = threadIdx.x, w = t >> 6, lane = t & 63, q = lane >> 4, c = lane & 15;
    int lo = 0, hi = N_NODES;
    while (lo < hi) { int mid = (lo + hi) >> 1; if (gid[mid] < b) lo = mid + 1; else hi = mid; }
    int s = lo;
    lo = 0; hi = N_NODES;
    while (lo < hi) { int mid = (lo + hi) >> 1; if (gid[mid] < b + 1) lo = mid + 1; else hi = mid; }
    int e = lo;
    int len = e - s;
    int ps = s + (int)(((long long)len * part) >> 3);
    int pe = s + (int)(((long long)len * (part + 1)) >> 3);

    float a0 = 0.f, a1 = 0.f, a2 = 0.f, a3 = 0.f, den = 0.f;
    for (int n0 = ps + w * 4; n0 < pe; n0 += 16) {
        int node = n0 + q;
        if (node < pe) {
            float gate = __expf(fminf(g[node], 30.f));
            uint2 raw = *(const uint2*)(x + (size_t)node * 64 + c * 4);
            a0 = fmaf(gate, asfloat(raw.x << 16), a0);
            a1 = fmaf(gate, asfloat(raw.x & 0xffff0000u), a1);
            a2 = fmaf(gate, asfloat(raw.y << 16), a2);
            a3 = fmaf(gate, asfloat(raw.y & 0xffff0000u), a3);
            if (c == 0) den += gate;
        }
    }
#pragma unroll
    for (int mm = 16; mm < 64; mm <<= 1) {
        a0 += __shfl_xor(a0, mm); a1 += __shfl_xor(a1, mm);
        a2 += __shfl_xor(a2, mm); a3 += __shfl_xor(a3, mm);
        den += __shfl_xor(den, mm);
    }
    __shared__ float snum[4][64];
    __shared__ float sden[4];
    if (lane < 16) {
        snum[w][c * 4 + 0] = a0; snum[w][c * 4 + 1] = a1;
        snum[w][c * 4 + 2] = a2; snum[w][c * 4 + 3] = a3;
        if (lane == 0) sden[w] = den;
    }
    __syncthreads();
    if (t < 64) pnum[((size_t)b * 8 + part) * 64 + t] = snum[0][t] + snum[1][t] + snum[2][t] + snum[3][t];
    if (t == 0) pden[b * 8 + part] = sden[0] + sden[1] + sden[2] + sden[3];
}

// ---------------- fused: ft = X @ W (MFMA, fp8 output) + el/er  |  GAP partials ----------------
__global__ __launch_bounds__(256) void k_ftgap(const u16* __restrict__ X, const u16* __restrict__ Wt,
                                               const float* __restrict__ al, const float* __restrict__ ar,
                                               u8* __restrict__ ft, float* __restrict__ el, float* __restrict__ er,
                                               const float* __restrict__ g, const int* __restrict__ gid,
                                               float* __restrict__ pnum, float* __restrict__ pden) {
    if (blockIdx.x >= FT_B) {
        gap_part(blockIdx.x - FT_B, X, g, gid, pnum, pden);
        return;
    }
    int w = threadIdx.x >> 6;
    int lane = threadIdx.x & 63;
    int quad = lane >> 4, c = lane & 15;
    int n0 = blockIdx.x * 16;

    f32x4 acc[4];
#pragma unroll
    for (int t = 0; t < 4; t++) acc[t] = (f32x4){0.f, 0.f, 0.f, 0.f};

#pragma unroll
    for (int kh = 0; kh < 2; kh++) {
        s16x8 a = *(const s16x8*)(X + (size_t)(n0 + c) * 64 + kh * 32 + quad * 8);
#pragma unroll
        for (int t = 0; t < 4; t++) {
            int col = w * 64 + t * 16 + c;
            s16x8 b = *(const s16x8*)(Wt + (size_t)col * 64 + kh * 32 + quad * 8);
            acc[t] = __builtin_amdgcn_mfma_f32_16x16x32_bf16(a, b, acc[t], 0, 0, 0);
        }
    }

    __shared__ u8 sft[16 * 256];   // fp8 tile
    float alv[4], arv[4];
#pragma unroll
    for (int t = 0; t < 4; t++) {
        alv[t] = al[w * 64 + t * 16 + c];
        arv[t] = ar[w * 64 + t * 16 + c];
    }
    float pel[4] = {0.f, 0.f, 0.f, 0.f}, per[4] = {0.f, 0.f, 0.f, 0.f};
#pragma unroll
    for (int t = 0; t < 4; t++) {
#pragma unroll
        for (int r = 0; r < 4; r++) {
            float v = acc[t][r];
            int nl = quad * 4 + r;
            int d = t * 16 + c;
            int pk = __builtin_amdgcn_cvt_pk_fp8_f32(v, v, 0, false);
            sft[nl * 256 + d * 4 + w] = (u8)(pk & 0xff);
            pel[r] += v * alv[t];
            per[r] += v * arv[t];
        }
    }
#pragma unroll
    for (int r = 0; r < 4; r++) {
#pragma unroll
        for (int mm = 1; mm < 16; mm <<= 1) {
            pel[r] += __shfl_xor(pel[r], mm);
            per[r] += __shfl_xor(per[r], mm);
        }
    }
    if (c == 0) {
#pragma unroll
        for (int r = 0; r < 4; r++) {
            int node = n0 + quad * 4 + r;
            el[node * 4 + w] = pel[r];
            er[node * 4 + w] = per[r];
        }
    }
    __syncthreads();
    const uint4* s4 = (const uint4*)sft;
    uint4* g4 = (uint4*)(ft + (size_t)n0 * 256);
    g4[threadIdx.x] = s4[threadIdx.x];
}

// ---------------- per-dst-node edge softmax + aggregation (wave per node, fp8 gather) ----------------
__global__ __launch_bounds__(256) void k_agg(
    const u8* __restrict__ ft, const float4* __restrict__ el4, const float4* __restrict__ er4,
    const int* __restrict__ rowptr, const int2* __restrict__ csr_se,
    const float* __restrict__ bias, const float* __restrict__ Wg, const float* __restrict__ bg,
    u16* __restrict__ hout, float* __restrict__ gout) {
    int wv = threadIdx.x >> 6;
    int node = blockIdx.x * 4 + wv;
    int lane = threadIdx.x & 63;
    int beg = rowptr[node], end = rowptr[node + 1];
    float4 erv = er4[node];

    __shared__ int    s_off[4][64];
    __shared__ float4 s_p[4][64];

    float S0 = 0.f, S1 = 0.f, S2 = 0.f, S3 = 0.f;
    float a0 = 0.f, a1 = 0.f, a2 = 0.f, a3 = 0.f;

    const char* ftl = (const char*)ft + lane * 4;

    for (int base = beg; base < end; base += 64) {
        int cnt = end - base; if (cnt > 64) cnt = 64;
        if (lane < cnt) {
            int2 se = csr_se[base + lane];
            int sidx = se.x;
            float w = asfloat((unsigned)se.y);
            float4 elv = el4[sidx];
            float t0 = elv.x + erv.x, t1 = elv.y + erv.y, t2 = elv.z + erv.z, t3 = elv.w + erv.w;
            t0 = t0 > 0.f ? t0 : 0.2f * t0;
            t1 = t1 > 0.f ? t1 : 0.2f * t1;
            t2 = t2 > 0.f ? t2 : 0.2f * t2;
            t3 = t3 > 0.f ? t3 : 0.2f * t3;
            float p0 = __expf(fminf(t0, 30.f));
            float p1 = __expf(fminf(t1, 30.f));
            float p2 = __expf(fminf(t2, 30.f));
            float p3 = __expf(fminf(t3, 30.f));
            S0 += p0; S1 += p1; S2 += p2; S3 += p3;
            s_off[wv][lane] = sidx * 256;
            s_p[wv][lane] = make_float4(p0 * w, p1 * w, p2 * w, p3 * w);
        }
        int k = 0;
        for (; k + 4 <= cnt; k += 4) {
            int o0 = s_off[wv][k], o1 = s_off[wv][k + 1], o2 = s_off[wv][k + 2], o3 = s_off[wv][k + 3];
            unsigned r0 = *(const unsigned*)(ftl + o0);
            unsigned r1 = *(const unsigned*)(ftl + o1);
            unsigned r2 = *(const unsigned*)(ftl + o2);
            unsigned r3 = *(const unsigned*)(ftl + o3);
            float4 q0 = s_p[wv][k], q1 = s_p[wv][k + 1], q2 = s_p[wv][k + 2], q3 = s_p[wv][k + 3];
            f32x2 l0 = __builtin_amdgcn_cvt_pk_f32_fp8(r0, false), h0 = __builtin_amdgcn_cvt_pk_f32_fp8(r0, true);
            f32x2 l1 = __builtin_amdgcn_cvt_pk_f32_fp8(r1, false), h1 = __builtin_amdgcn_cvt_pk_f32_fp8(r1, true);
            f32x2 l2 = __builtin_amdgcn_cvt_pk_f32_fp8(r2, false), h2 = __builtin_amdgcn_cvt_pk_f32_fp8(r2, true);
            f32x2 l3 = __builtin_amdgcn_cvt_pk_f32_fp8(r3, false), h3 = __builtin_amdgcn_cvt_pk_f32_fp8(r3, true);
            a0 = fmaf(q0.x, l0.x, a0); a1 = fmaf(q0.y, l0.y, a1);
            a2 = fmaf(q0.z, h0.x, a2); a3 = fmaf(q0.w, h0.y, a3);
            a0 = fmaf(q1.x, l1.x, a0); a1 = fmaf(q1.y, l1.y, a1);
            a2 = fmaf(q1.z, h1.x, a2); a3 = fmaf(q1.w, h1.y, a3);
            a0 = fmaf(q2.x, l2.x, a0); a1 = fmaf(q2.y, l2.y, a1);
            a2 = fmaf(q2.z, h2.x, a2); a3 = fmaf(q2.w, h2.y, a3);
            a0 = fmaf(q3.x, l3.x, a0); a1 = fmaf(q3.y, l3.y, a1);
            a2 = fmaf(q3.z, h3.x, a2); a3 = fmaf(q3.w, h3.y, a3);
        }
        for (; k < cnt; k++) {
            int o0 = s_off[wv][k];
            float4 q0 = s_p[wv][k];
            unsigned r0 = *(const unsigned*)(ftl + o0);
            f32x2 l0 = __builtin_amdgcn_cvt_pk_f32_fp8(r0, false), h0 = __builtin_amdgcn_cvt_pk_f32_fp8(r0, true);
            a0 = fmaf(q0.x, l0.x, a0); a1 = fmaf(q0.y, l0.y, a1);
            a2 = fmaf(q0.z, h0.x, a2); a3 = fmaf(q0.w, h0.y, a3);
        }
    }
#pragma unroll
    for (int mm = 1; mm < 64; mm <<= 1) {
        S0 += __shfl_xor(S0, mm);
        S1 += __shfl_xor(S1, mm);
        S2 += __shfl_xor(S2, mm);
        S3 += __shfl_xor(S3, mm);
    }
    float i0 = S0 > 0.f ? 1.f / S0 : 0.f;
    float i1 = S1 > 0.f ? 1.f / S1 : 0.f;
    float i2 = S2 > 0.f ? 1.f / S2 : 0.f;
    float i3 = S3 > 0.f ? 1.f / S3 : 0.f;
    float r0 = a0 * i0 + bias[lane];
    float r1 = a1 * i1 + bias[64 + lane];
    float r2 = a2 * i2 + bias[128 + lane];
    float r3 = a3 * i3 + bias[192 + lane];
    float o = (fmaxf(r0, 0.f) + fmaxf(r1, 0.f) + fmaxf(r2, 0.f) + fmaxf(r3, 0.f)) * 0.25f;
    hout[(size_t)node * 64 + lane] = f2bf(o);
    float pg = o * Wg[lane];
#pragma unroll
    for (int mm = 1; mm < 64; mm <<= 1) pg += __shfl_xor(pg, mm);
    if (lane == 0) gout[node] = pg + bg[0];
}

// ---------------- standalone GAP (final layer) ----------------
__global__ __launch_bounds__(256) void k_gapP(const u16* __restrict__ x, const float* __restrict__ g,
                                              const int* __restrict__ gid,
                                              float* __restrict__ pnum, float* __restrict__ pden) {
    gap_part(blockIdx.x, x, g, gid, pnum, pden);
}

// ---------------- LSTM (4 steps) + final linear + sigmoid; combines gap partials ----------------
__global__ __launch_bounds__(256) void k_lstm(const float* __restrict__ pnum, const float* __restrict__ pden,
                                              const float* __restrict__ Wih, const float* __restrict__ Whh,
                                              const float* __restrict__ bih, const float* __restrict__ bhh,
                                              const float* __restrict__ Wc, const float* __restrict__ bc,
                                              float* __restrict__ out) {
    int b = blockIdx.x, t = threadIdx.x;
    __shared__ float h[64], c[64], G[256], xv[64], red[64];
    if (t < 64) { h[t] = 0.f; c[t] = 0.f; }
    __syncthreads();
    for (int step = 0; step < 4; step++) {
        if (t < 64) {
            const float* pn = pnum + (((size_t)step * N_GRAPHS + b) * 8) * 64;
            const float* pd = pden + ((size_t)step * N_GRAPHS + b) * 8;
            float num = 0.f, dn = 0.f;
#pragma unroll
            for (int pp = 0; pp < 8; pp++) { num += pn[pp * 64 + t]; dn += pd[pp]; }
            xv[t] = (dn > 0.f) ? num / dn : 0.f;
        }
        __syncthreads();
        float acc = bih[t] + bhh[t];
#pragma unroll 4
        for (int d = 0; d < 64; d++)
            acc += xv[d] * Wih[t * 64 + d] + h[d] * Whh[t * 64 + d];
        G[t] = acc;
        __syncthreads();
        if (t < 64) {
            float ig = 1.f / (1.f + __expf(-G[t]));
            float fg = 1.f / (1.f + __expf(-G[64 + t]));
            float gg = tanhf(G[128 + t]);
            float og = 1.f / (1.f + __expf(-G[192 + t]));
            float cn = fg * c[t] + ig * gg;
            c[t] = cn;
            h[t] = og * tanhf(cn);
        }
        __syncthreads();
    }
    if (t < 64) red[t] = h[t] * Wc[t];
    __syncthreads();
    if (t == 0) {
        float r = 0.f;
        for (int i = 0; i < 64; i++) r += red[i];
        r += bc[0];
        out[b] = 1.f / (1.f + __expf(-r));
    }
}

extern "C" void kernel_launch(void* const* d_in, const int* in_sizes, int n_in,
                              void* d_out, int out_size, void* d_ws, size_t ws_size,
                              hipStream_t stream) {
    const float* nf   = (const float*)d_in[0];
    const float* nm   = (const float*)d_in[1];
    const float* cent = (const float*)d_in[2];
    const float* ew   = (const float*)d_in[3];
    const int* src  = (const int*)d_in[4];
    const int* dst  = (const int*)d_in[5];
    const int* gid  = (const int*)d_in[6];
    const float* W[3]  = {(const float*)d_in[7],  (const float*)d_in[11], (const float*)d_in[15]};
    const float* al[3] = {(const float*)d_in[8],  (const float*)d_in[12], (const float*)d_in[16]};
    const float* ar[3] = {(const float*)d_in[9],  (const float*)d_in[13], (const float*)d_in[17]};
    const float* bb[3] = {(const float*)d_in[10], (const float*)d_in[14], (const float*)d_in[18]};
    const float* Wg[4] = {(const float*)d_in[19], (const float*)d_in[21], (const float*)d_in[23], (const float*)d_in[25]};
    const float* bg[4] = {(const float*)d_in[20], (const float*)d_in[22], (const float*)d_in[24], (const float*)d_in[26]};
    const float* Wih = (const float*)d_in[27];
    const float* Whh = (const float*)d_in[28];
    const float* bih = (const float*)d_in[29];
    const float* bhh = (const float*)d_in[30];
    const float* Wc  = (const float*)d_in[31];
    const float* bc  = (const float*)d_in[32];
    float* out = (float*)d_out;

    char* p = (char*)d_ws;
    size_t off = 0;
    auto A = [&](size_t bytes) -> char* {
        char* r = p + off;
        off += (bytes + 255) & ~(size_t)255;
        return r;
    };
    u8*    ftb     = (u8*)   A((size_t)N_NODES * 256);       // 12.8 MB fp8
    u16*   nodebuf = (u16*)  A((size_t)N_NODES * 64 * 2);    // 6.4 MB
    int2*  csr_se  = (int2*) A((size_t)N_EDGES * 8);         // 6.4 MB packed (src, ew)
    int2*  binse   = (int2*) A((size_t)SCAN_B * SHARDS * BCAP * 8);  // 8.8 MB
    u8*    dstlo   = (u8*)   A((size_t)SCAN_B * SHARDS * BCAP);      // 1.1 MB
    float* el      = (float*)A((size_t)N_NODES * 4 * 4);
    float* er      = (float*)A((size_t)N_NODES * 4 * 4);
    float* gbuf    = (float*)A((size_t)N_NODES * 4);
    int*   rowptr  = (int*)  A((size_t)(N_NODES + 1) * 4);
    int*   deg     = (int*)  A((size_t)(N_NODES + 1) * 4);   // zeroed region start
    int*   cnt     = (int*)  A((size_t)SCAN_B * SHARDS * 4); // contiguous after deg
    float* pnum    = (float*)A((size_t)4 * N_GRAPHS * 8 * 64 * 4);
    float* pden    = (float*)A((size_t)4 * N_GRAPHS * 8 * 4);
    int*   bsum    = (int*)  A((size_t)SCAN_B * 4);
    int*   boff    = (int*)  A((size_t)SCAN_B * 4);
    u16*   Wt      = (u16*)  A((size_t)3 * 64 * 256 * 2);

    k_init<<<SCAN_B + N_NODES / 4, 256, 0, stream>>>(nf, nm, cent, Wg[0], bg[0], nodebuf, gbuf, deg);
    k_bin<<<(N_EDGES + 255) / 256, 256, 0, stream>>>(src, dst, ew, deg, cnt, binse, dstlo);
    k_scanA<<<SCAN_B, 256, 0, stream>>>(deg, rowptr, bsum);
    k_scanBprep<<<13, 256, 0, stream>>>(bsum, boff, W[0], W[1], W[2], Wt);
    k_csr<<<SCAN_B, 256, 0, stream>>>(rowptr, deg, boff, cnt, binse, dstlo, csr_se);

    for (int l = 0; l < 3; l++) {
        k_ftgap<<<FT_B + GAP_B, 256, 0, stream>>>(nodebuf, Wt + (size_t)l * 64 * 256, al[l], ar[l],
                                                  ftb, el, er, gbuf, gid,
                                                  pnum + (size_t)l * N_GRAPHS * 8 * 64,
                                                  pden + (size_t)l * N_GRAPHS * 8);
        k_agg<<<N_NODES / 4, 256, 0, stream>>>(ftb, (const float4*)el, (const float4*)er, rowptr,
                                               csr_se, bb[l], Wg[l + 1], bg[l + 1], nodebuf, gbuf);
    }
    k_gapP<<<GAP_B, 256, 0, stream>>>(nodebuf, gbuf, gid,
                                      pnum + (size_t)3 * N_GRAPHS * 8 * 64,
                                      pden + (size_t)3 * N_GRAPHS * 8);
    k_lstm<<<N_GRAPHS, 256, 0, stream>>>(pnum, pden, Wih, Whh, bih, bhh, Wc, bc, out);
}

// Round 11
// 441.851 us; speedup vs baseline: 1.3248x; 1.3248x over previous
//
#include <hip/hip_runtime.h>
#include <hip/hip_bf16.h>

#define N_NODES 50000
#define N_EDGES 800000
#define N_GRAPHS 64
#define SCAN_B 196   // ceil(N_NODES/256)
#define FT_B   3125  // N_NODES/16
#define GAP_B  512   // 64 graphs * 8 parts

typedef unsigned short u16;
typedef unsigned char u8;
typedef unsigned int u32;
typedef short s16x8 __attribute__((ext_vector_type(8)));
typedef float f32x4 __attribute__((ext_vector_type(4)));
typedef float f32x2 __attribute__((ext_vector_type(2)));

__device__ __forceinline__ float bf2f(u16 u) {
    union { unsigned int i; float f; } v; v.i = ((unsigned int)u) << 16; return v.f;
}
__device__ __forceinline__ u16 f2bf(float f) {
    union { float f; unsigned int i; } v; v.f = f;
    unsigned int i = v.i;
    unsigned int r = i + 0x7fffu + ((i >> 16) & 1u);
    return (u16)(r >> 16);
}
__device__ __forceinline__ float asfloat(unsigned int u) {
    union { unsigned int i; float f; } v; v.i = u; return v.f;
}

// ---------------- fused: zero deg + (x = concat*centrality, gate logit) ----------------
__global__ __launch_bounds__(256) void k_init(const float* __restrict__ nf, const float* __restrict__ nm,
                                              const float* __restrict__ cent, const float* __restrict__ Wg,
                                              const float* __restrict__ bg,
                                              u16* __restrict__ x, float* __restrict__ g,
                                              int* __restrict__ deg) {
    int b = blockIdx.x;
    if (b < SCAN_B) {                 // zero deg[0..N_NODES]
        int i = b * 256 + threadIdx.x;
        if (i <= N_NODES) deg[i] = 0;
        return;
    }
    b -= SCAN_B;
    int node = b * 4 + (threadIdx.x >> 6);
    int lane = threadIdx.x & 63;
    float v = (lane < 48) ? nf[(size_t)node * 48 + lane] : nm[(size_t)node * 16 + lane - 48];
    float xf = v * cent[node];
    x[(size_t)node * 64 + lane] = f2bf(xf);
    float p = xf * Wg[lane];
#pragma unroll
    for (int mm = 1; mm < 64; mm <<= 1) p += __shfl_xor(p, mm);
    if (lane == 0) g[node] = p + bg[0];
}

// ---------------- CSR build (by dst) ----------------
__global__ __launch_bounds__(256) void k_hist(const int* __restrict__ dst, int* __restrict__ deg) {
    int e = blockIdx.x * 256 + threadIdx.x;
    if (e < N_EDGES) atomicAdd(&deg[dst[e]], 1);
}

__global__ __launch_bounds__(256) void k_scanA(const int* __restrict__ deg,
                                               int* __restrict__ rowptr, int* __restrict__ bsum) {
    int b = blockIdx.x, t = threadIdx.x;
    int i = b * 256 + t;
    int v = (i < N_NODES) ? deg[i] : 0;
    int orig = v;
    int lane = t & 63, w = t >> 6;
#pragma unroll
    for (int d = 1; d < 64; d <<= 1) {
        int u = __shfl_up(v, d);
        if (lane >= d) v += u;
    }
    __shared__ int wsum[4];
    if (lane == 63) wsum[w] = v;
    __syncthreads();
    int add = 0;
    for (int k = 0; k < w; k++) add += wsum[k];
    v += add;
    if (i < N_NODES) rowptr[i] = v - orig;
    if (t == 255) bsum[b] = v;
}

// fused: block 0 = scan of block sums; blocks 1..12 = W transpose (independent)
__global__ __launch_bounds__(256) void k_scanBprep(const int* __restrict__ bsum, int* __restrict__ boff,
                                                   const float* __restrict__ W1, const float* __restrict__ W2,
                                                   const float* __restrict__ W3, u16* __restrict__ Wt) {
    __shared__ float tile[64][65];
    __shared__ int wsum[4];
    if (blockIdx.x == 0) {
        int t = threadIdx.x;
        int v = (t < SCAN_B) ? bsum[t] : 0;
        int orig = v;
        int lane = t & 63, w = t >> 6;
#pragma unroll
        for (int d = 1; d < 64; d <<= 1) {
            int u = __shfl_up(v, d);
            if (lane >= d) v += u;
        }
        if (lane == 63) wsum[w] = v;
        __syncthreads();
        int add = 0;
        for (int k = 0; k < w; k++) add += wsum[k];
        v += add;
        if (t < SCAN_B) boff[t] = v - orig;
        return;
    }
    int bb = blockIdx.x - 1;
    int l = bb >> 2, ti = bb & 3;
    const float* W = (l == 0) ? W1 : (l == 1) ? W2 : W3;
    u16* o = Wt + (size_t)l * 64 * 256;
    int t = threadIdx.x;
    for (int i = t; i < 64 * 64; i += 256) {
        int d = i >> 6, c = i & 63;
        tile[d][c] = W[d * 256 + ti * 64 + c];
    }
    __syncthreads();
    for (int i = t; i < 64 * 64; i += 256) {
        int c = i >> 6, d = i & 63;
        o[(size_t)(ti * 64 + c) * 64 + d] = f2bf(tile[d][c]);
    }
}

__global__ __launch_bounds__(256) void k_scanC(const int* __restrict__ boff,
                                               int* __restrict__ rowptr, int* __restrict__ deg) {
    int b = blockIdx.x, t = threadIdx.x;
    int i = b * 256 + t;
    if (i < N_NODES) {
        int val = rowptr[i] + boff[b];
        int d = deg[i];
        rowptr[i] = val;
        deg[i] = val;
        if (i == N_NODES - 1) rowptr[N_NODES] = val + d;
    }
}

// packed (ew_bf16 << 16 | src) scatter: ONE 4B random write per edge (src < 2^16 guaranteed at N=50000... 50000<65536)
__global__ __launch_bounds__(256) void k_scatter(const int* __restrict__ src, const int* __restrict__ dst,
                                                 const float* __restrict__ ew, int* __restrict__ cursor,
                                                 u32* __restrict__ csr_se) {
    int e = blockIdx.x * 256 + threadIdx.x;
    if (e < N_EDGES) {
        int d = dst[e];
        int pos = atomicAdd(&cursor[d], 1);
        csr_se[pos] = ((u32)f2bf(ew[e]) << 16) | (u32)src[e];
    }
}

// ---------------- GAP partial (device fn): 8 parts/graph, no-max exp ----------------
__device__ __forceinline__ void gap_part(int pb, const u16* __restrict__ x, const float* __restrict__ g,
                                         const int* __restrict__ gid,
                                         float* __restrict__ pnum, float* __restrict__ pden) {
    int part = pb & 7, b = pb >> 3;
    int t = threadIdx.x, w = t >> 6, lane = t & 63, q = lane >> 4, c = lane & 15;
    int lo = 0, hi = N_NODES;
    while (lo < hi) { int mid = (lo + hi) >> 1; if (gid[mid] < b) lo = mid + 1; else hi = mid; }
    int s = lo;
    lo = 0; hi = N_NODES;
    while (lo < hi) { int mid = (lo + hi) >> 1; if (gid[mid] < b + 1) lo = mid + 1; else hi = mid; }
    int e = lo;
    int len = e - s;
    int ps = s + (int)(((long long)len * part) >> 3);
    int pe = s + (int)(((long long)len * (part + 1)) >> 3);

    float a0 = 0.f, a1 = 0.f, a2 = 0.f, a3 = 0.f, den = 0.f;
    for (int n0 = ps + w * 4; n0 < pe; n0 += 16) {
        int node = n0 + q;
        if (node < pe) {
            float gate = __expf(fminf(g[node], 30.f));
            uint2 raw = *(const uint2*)(x + (size_t)node * 64 + c * 4);
            a0 = fmaf(gate, asfloat(raw.x << 16), a0);
            a1 = fmaf(gate, asfloat(raw.x & 0xffff0000u), a1);
            a2 = fmaf(gate, asfloat(raw.y << 16), a2);
            a3 = fmaf(gate, asfloat(raw.y & 0xffff0000u), a3);
            if (c == 0) den += gate;
        }
    }
#pragma unroll
    for (int mm = 16; mm < 64; mm <<= 1) {
        a0 += __shfl_xor(a0, mm); a1 += __shfl_xor(a1, mm);
        a2 += __shfl_xor(a2, mm); a3 += __shfl_xor(a3, mm);
        den += __shfl_xor(den, mm);
    }
    __shared__ float snum[4][64];
    __shared__ float sden[4];
    if (lane < 16) {
        snum[w][c * 4 + 0] = a0; snum[w][c * 4 + 1] = a1;
        snum[w][c * 4 + 2] = a2; snum[w][c * 4 + 3] = a3;
        if (lane == 0) sden[w] = den;
    }
    __syncthreads();
    if (t < 64) pnum[((size_t)b * 8 + part) * 64 + t] = snum[0][t] + snum[1][t] + snum[2][t] + snum[3][t];
    if (t == 0) pden[b * 8 + part] = sden[0] + sden[1] + sden[2] + sden[3];
}

// ---------------- fused: ft = X @ W (MFMA, fp8 output) + el/er  |  GAP partials ----------------
__global__ __launch_bounds__(256) void k_ftgap(const u16* __restrict__ X, const u16* __restrict__ Wt,
                                               const float* __restrict__ al, const float* __restrict__ ar,
                                               u8* __restrict__ ft, float* __restrict__ el, float* __restrict__ er,
                                               const float* __restrict__ g, const int* __restrict__ gid,
                                               float* __restrict__ pnum, float* __restrict__ pden) {
    if (blockIdx.x >= FT_B) {
        gap_part(blockIdx.x - FT_B, X, g, gid, pnum, pden);
        return;
    }
    int w = threadIdx.x >> 6;
    int lane = threadIdx.x & 63;
    int quad = lane >> 4, c = lane & 15;
    int n0 = blockIdx.x * 16;

    f32x4 acc[4];
#pragma unroll
    for (int t = 0; t < 4; t++) acc[t] = (f32x4){0.f, 0.f, 0.f, 0.f};

#pragma unroll
    for (int kh = 0; kh < 2; kh++) {
        s16x8 a = *(const s16x8*)(X + (size_t)(n0 + c) * 64 + kh * 32 + quad * 8);
#pragma unroll
        for (int t = 0; t < 4; t++) {
            int col = w * 64 + t * 16 + c;
            s16x8 b = *(const s16x8*)(Wt + (size_t)col * 64 + kh * 32 + quad * 8);
            acc[t] = __builtin_amdgcn_mfma_f32_16x16x32_bf16(a, b, acc[t], 0, 0, 0);
        }
    }

    __shared__ u8 sft[16 * 256];   // fp8 tile
    float alv[4], arv[4];
#pragma unroll
    for (int t = 0; t < 4; t++) {
        alv[t] = al[w * 64 + t * 16 + c];
        arv[t] = ar[w * 64 + t * 16 + c];
    }
    float pel[4] = {0.f, 0.f, 0.f, 0.f}, per[4] = {0.f, 0.f, 0.f, 0.f};
#pragma unroll
    for (int t = 0; t < 4; t++) {
#pragma unroll
        for (int r = 0; r < 4; r++) {
            float v = acc[t][r];
            int nl = quad * 4 + r;
            int d = t * 16 + c;
            int pk = __builtin_amdgcn_cvt_pk_fp8_f32(v, v, 0, false);
            sft[nl * 256 + d * 4 + w] = (u8)(pk & 0xff);
            pel[r] += v * alv[t];
            per[r] += v * arv[t];
        }
    }
#pragma unroll
    for (int r = 0; r < 4; r++) {
#pragma unroll
        for (int mm = 1; mm < 16; mm <<= 1) {
            pel[r] += __shfl_xor(pel[r], mm);
            per[r] += __shfl_xor(per[r], mm);
        }
    }
    if (c == 0) {
#pragma unroll
        for (int r = 0; r < 4; r++) {
            int node = n0 + quad * 4 + r;
            el[node * 4 + w] = pel[r];
            er[node * 4 + w] = per[r];
        }
    }
    __syncthreads();
    const uint4* s4 = (const uint4*)sft;
    uint4* g4 = (uint4*)(ft + (size_t)n0 * 256);
    g4[threadIdx.x] = s4[threadIdx.x];
}

// ---------------- per-dst-node edge softmax + aggregation (wave per node, fp8 gather) ----------------
__global__ __launch_bounds__(256) void k_agg(
    const u8* __restrict__ ft, const float4* __restrict__ el4, const float4* __restrict__ er4,
    const int* __restrict__ rowptr, const u32* __restrict__ csr_se,
    const float* __restrict__ bias, const float* __restrict__ Wg, const float* __restrict__ bg,
    u16* __restrict__ hout, float* __restrict__ gout) {
    int wv = threadIdx.x >> 6;
    int node = blockIdx.x * 4 + wv;
    int lane = threadIdx.x & 63;
    int beg = rowptr[node], end = rowptr[node + 1];
    float4 erv = er4[node];

    __shared__ int    s_off[4][64];
    __shared__ float4 s_p[4][64];

    float S0 = 0.f, S1 = 0.f, S2 = 0.f, S3 = 0.f;
    float a0 = 0.f, a1 = 0.f, a2 = 0.f, a3 = 0.f;

    const char* ftl = (const char*)ft + lane * 4;

    for (int base = beg; base < end; base += 64) {
        int cnt = end - base; if (cnt > 64) cnt = 64;
        if (lane < cnt) {
            u32 se = csr_se[base + lane];
            int sidx = (int)(se & 0xffffu);
            float w = bf2f((u16)(se >> 16));
            float4 elv = el4[sidx];
            float t0 = elv.x + erv.x, t1 = elv.y + erv.y, t2 = elv.z + erv.z, t3 = elv.w + erv.w;
            t0 = t0 > 0.f ? t0 : 0.2f * t0;
            t1 = t1 > 0.f ? t1 : 0.2f * t1;
            t2 = t2 > 0.f ? t2 : 0.2f * t2;
            t3 = t3 > 0.f ? t3 : 0.2f * t3;
            float p0 = __expf(fminf(t0, 30.f));
            float p1 = __expf(fminf(t1, 30.f));
            float p2 = __expf(fminf(t2, 30.f));
            float p3 = __expf(fminf(t3, 30.f));
            S0 += p0; S1 += p1; S2 += p2; S3 += p3;
            s_off[wv][lane] = sidx * 256;
            s_p[wv][lane] = make_float4(p0 * w, p1 * w, p2 * w, p3 * w);
        }
        int k = 0;
        for (; k + 4 <= cnt; k += 4) {
            int o0 = s_off[wv][k], o1 = s_off[wv][k + 1], o2 = s_off[wv][k + 2], o3 = s_off[wv][k + 3];
            unsigned r0 = *(const unsigned*)(ftl + o0);
            unsigned r1 = *(const unsigned*)(ftl + o1);
            unsigned r2 = *(const unsigned*)(ftl + o2);
            unsigned r3 = *(const unsigned*)(ftl + o3);
            float4 q0 = s_p[wv][k], q1 = s_p[wv][k + 1], q2 = s_p[wv][k + 2], q3 = s_p[wv][k + 3];
            f32x2 l0 = __builtin_amdgcn_cvt_pk_f32_fp8(r0, false), h0 = __builtin_amdgcn_cvt_pk_f32_fp8(r0, true);
            f32x2 l1 = __builtin_amdgcn_cvt_pk_f32_fp8(r1, false), h1 = __builtin_amdgcn_cvt_pk_f32_fp8(r1, true);
            f32x2 l2 = __builtin_amdgcn_cvt_pk_f32_fp8(r2, false), h2 = __builtin_amdgcn_cvt_pk_f32_fp8(r2, true);
            f32x2 l3 = __builtin_amdgcn_cvt_pk_f32_fp8(r3, false), h3 = __builtin_amdgcn_cvt_pk_f32_fp8(r3, true);
            a0 = fmaf(q0.x, l0.x, a0); a1 = fmaf(q0.y, l0.y, a1);
            a2 = fmaf(q0.z, h0.x, a2); a3 = fmaf(q0.w, h0.y, a3);
            a0 = fmaf(q1.x, l1.x, a0); a1 = fmaf(q1.y, l1.y, a1);
            a2 = fmaf(q1.z, h1.x, a2); a3 = fmaf(q1.w, h1.y, a3);
            a0 = fmaf(q2.x, l2.x, a0); a1 = fmaf(q2.y, l2.y, a1);
            a2 = fmaf(q2.z, h2.x, a2); a3 = fmaf(q2.w, h2.y, a3);
            a0 = fmaf(q3.x, l3.x, a0); a1 = fmaf(q3.y, l3.y, a1);
            a2 = fmaf(q3.z, h3.x, a2); a3 = fmaf(q3.w, h3.y, a3);
        }
        for (; k < cnt; k++) {
            int o0 = s_off[wv][k];
            float4 q0 = s_p[wv][k];
            unsigned r0 = *(const unsigned*)(ftl + o0);
            f32x2 l0 = __builtin_amdgcn_cvt_pk_f32_fp8(r0, false), h0 = __builtin_amdgcn_cvt_pk_f32_fp8(r0, true);
            a0 = fmaf(q0.x, l0.x, a0); a1 = fmaf(q0.y, l0.y, a1);
            a2 = fmaf(q0.z, h0.x, a2); a3 = fmaf(q0.w, h0.y, a3);
        }
    }
#pragma unroll
    for (int mm = 1; mm < 64; mm <<= 1) {
        S0 += __shfl_xor(S0, mm);
        S1 += __shfl_xor(S1, mm);
        S2 += __shfl_xor(S2, mm);
        S3 += __shfl_xor(S3, mm);
    }
    float i0 = S0 > 0.f ? 1.f / S0 : 0.f;
    float i1 = S1 > 0.f ? 1.f / S1 : 0.f;
    float i2 = S2 > 0.f ? 1.f / S2 : 0.f;
    float i3 = S3 > 0.f ? 1.f / S3 : 0.f;
    float r0 = a0 * i0 + bias[lane];
    float r1 = a1 * i1 + bias[64 + lane];
    float r2 = a2 * i2 + bias[128 + lane];
    float r3 = a3 * i3 + bias[192 + lane];
    float o = (fmaxf(r0, 0.f) + fmaxf(r1, 0.f) + fmaxf(r2, 0.f) + fmaxf(r3, 0.f)) * 0.25f;
    hout[(size_t)node * 64 + lane] = f2bf(o);
    float pg = o * Wg[lane];
#pragma unroll
    for (int mm = 1; mm < 64; mm <<= 1) pg += __shfl_xor(pg, mm);
    if (lane == 0) gout[node] = pg + bg[0];
}

// ---------------- standalone GAP (final layer) ----------------
__global__ __launch_bounds__(256) void k_gapP(const u16* __restrict__ x, const float* __restrict__ g,
                                              const int* __restrict__ gid,
                                              float* __restrict__ pnum, float* __restrict__ pden) {
    gap_part(blockIdx.x, x, g, gid, pnum, pden);
}

// ---------------- LSTM (4 steps) + final linear + sigmoid; combines gap partials ----------------
__global__ __launch_bounds__(256) void k_lstm(const float* __restrict__ pnum, const float* __restrict__ pden,
                                              const float* __restrict__ Wih, const float* __restrict__ Whh,
                                              const float* __restrict__ bih, const float* __restrict__ bhh,
                                              const float* __restrict__ Wc, const float* __restrict__ bc,
                                              float* __restrict__ out) {
    int b = blockIdx.x, t = threadIdx.x;
    __shared__ float h[64], c[64], G[256], xv[64], red[64];
    if (t < 64) { h[t] = 0.f; c[t] = 0.f; }
    __syncthreads();
    for (int step = 0; step < 4; step++) {
        if (t < 64) {
            const float* pn = pnum + (((size_t)step * N_GRAPHS + b) * 8) * 64;
            const float* pd = pden + ((size_t)step * N_GRAPHS + b) * 8;
            float num = 0.f, dn = 0.f;
#pragma unroll
            for (int pp = 0; pp < 8; pp++) { num += pn[pp * 64 + t]; dn += pd[pp]; }
            xv[t] = (dn > 0.f) ? num / dn : 0.f;
        }
        __syncthreads();
        float acc = bih[t] + bhh[t];
#pragma unroll 4
        for (int d = 0; d < 64; d++)
            acc += xv[d] * Wih[t * 64 + d] + h[d] * Whh[t * 64 + d];
        G[t] = acc;
        __syncthreads();
        if (t < 64) {
            float ig = 1.f / (1.f + __expf(-G[t]));
            float fg = 1.f / (1.f + __expf(-G[64 + t]));
            float gg = tanhf(G[128 + t]);
            float og = 1.f / (1.f + __expf(-G[192 + t]));
            float cn = fg * c[t] + ig * gg;
            c[t] = cn;
            h[t] = og * tanhf(cn);
        }
        __syncthreads();
    }
    if (t < 64) red[t] = h[t] * Wc[t];
    __syncthreads();
    if (t == 0) {
        float r = 0.f;
        for (int i = 0; i < 64; i++) r += red[i];
        r += bc[0];
        out[b] = 1.f / (1.f + __expf(-r));
    }
}

extern "C" void kernel_launch(void* const* d_in, const int* in_sizes, int n_in,
                              void* d_out, int out_size, void* d_ws, size_t ws_size,
                              hipStream_t stream) {
    const float* nf   = (const float*)d_in[0];
    const float* nm   = (const float*)d_in[1];
    const float* cent = (const float*)d_in[2];
    const float* ew   = (const float*)d_in[3];
    const int* src  = (const int*)d_in[4];
    const int* dst  = (const int*)d_in[5];
    const int* gid  = (const int*)d_in[6];
    const float* W[3]  = {(const float*)d_in[7],  (const float*)d_in[11], (const float*)d_in[15]};
    const float* al[3] = {(const float*)d_in[8],  (const float*)d_in[12], (const float*)d_in[16]};
    const float* ar[3] = {(const float*)d_in[9],  (const float*)d_in[13], (const float*)d_in[17]};
    const float* bb[3] = {(const float*)d_in[10], (const float*)d_in[14], (const float*)d_in[18]};
    const float* Wg[4] = {(const float*)d_in[19], (const float*)d_in[21], (const float*)d_in[23], (const float*)d_in[25]};
    const float* bg[4] = {(const float*)d_in[20], (const float*)d_in[22], (const float*)d_in[24], (const float*)d_in[26]};
    const float* Wih = (const float*)d_in[27];
    const float* Whh = (const float*)d_in[28];
    const float* bih = (const float*)d_in[29];
    const float* bhh = (const float*)d_in[30];
    const float* Wc  = (const float*)d_in[31];
    const float* bc  = (const float*)d_in[32];
    float* out = (float*)d_out;

    char* p = (char*)d_ws;
    size_t off = 0;
    auto A = [&](size_t bytes) -> char* {
        char* r = p + off;
        off += (bytes + 255) & ~(size_t)255;
        return r;
    };
    u8*    ftb     = (u8*)   A((size_t)N_NODES * 256);       // 12.8 MB fp8
    u16*   nodebuf = (u16*)  A((size_t)N_NODES * 64 * 2);    // 6.4 MB
    u32*   csr_se  = (u32*)  A((size_t)N_EDGES * 4);         // 3.2 MB packed (ew_bf16 | src_u16)
    float* el      = (float*)A((size_t)N_NODES * 4 * 4);
    float* er      = (float*)A((size_t)N_NODES * 4 * 4);
    float* gbuf    = (float*)A((size_t)N_NODES * 4);
    int*   rowptr  = (int*)  A((size_t)(N_NODES + 1) * 4);
    int*   deg     = (int*)  A((size_t)(N_NODES + 1) * 4);   // becomes scatter cursor
    float* pnum    = (float*)A((size_t)4 * N_GRAPHS * 8 * 64 * 4);
    float* pden    = (float*)A((size_t)4 * N_GRAPHS * 8 * 4);
    int*   bsum    = (int*)  A((size_t)SCAN_B * 4);
    int*   boff    = (int*)  A((size_t)SCAN_B * 4);
    u16*   Wt      = (u16*)  A((size_t)3 * 64 * 256 * 2);

    k_init<<<SCAN_B + N_NODES / 4, 256, 0, stream>>>(nf, nm, cent, Wg[0], bg[0], nodebuf, gbuf, deg);
    k_hist<<<(N_EDGES + 255) / 256, 256, 0, stream>>>(dst, deg);
    k_scanA<<<SCAN_B, 256, 0, stream>>>(deg, rowptr, bsum);
    k_scanBprep<<<13, 256, 0, stream>>>(bsum, boff, W[0], W[1], W[2], Wt);
    k_scanC<<<SCAN_B, 256, 0, stream>>>(boff, rowptr, deg);
    k_scatter<<<(N_EDGES + 255) / 256, 256, 0, stream>>>(src, dst, ew, deg, csr_se);

    for (int l = 0; l < 3; l++) {
        k_ftgap<<<FT_B + GAP_B, 256, 0, stream>>>(nodebuf, Wt + (size_t)l * 64 * 256, al[l], ar[l],
                                                  ftb, el, er, gbuf, gid,
                                                  pnum + (size_t)l * N_GRAPHS * 8 * 64,
                                                  pden + (size_t)l * N_GRAPHS * 8);
        k_agg<<<N_NODES / 4, 256, 0, stream>>>(ftb, (const float4*)el, (const float4*)er, rowptr,
                                               csr_se, bb[l], Wg[l + 1], bg[l + 1], nodebuf, gbuf);
    }
    k_gapP<<<GAP_B, 256, 0, stream>>>(nodebuf, gbuf, gid,
                                      pnum + (size_t)3 * N_GRAPHS * 8 * 64,
                                      pden + (size_t)3 * N_GRAPHS * 8);
    k_lstm<<<N_GRAPHS, 256, 0, stream>>>(pnum, pden, Wih, Whh, bih, bhh, Wc, bc, out);
}

// Round 12
// 386.781 us; speedup vs baseline: 1.5135x; 1.1424x over previous
//
#include <hip/hip_runtime.h>
#include <hip/hip_bf16.h>

#define N_NODES 50000
#define N_EDGES 800000
#define N_GRAPHS 64
#define SCAN_B 196   // ceil(N_NODES/256) = number of dst bins (256 nodes each)
#define FT_B   3125  // N_NODES/16
#define GAP_B  512   // 64 graphs * 8 parts
#define G1     784   // pass-1 segments
#define EPB    1024  // edges per segment (784*1024 >= 800000)

typedef unsigned short u16;
typedef unsigned char u8;
typedef unsigned int u32;
typedef short s16x8 __attribute__((ext_vector_type(8)));
typedef float f32x4 __attribute__((ext_vector_type(4)));
typedef float f32x2 __attribute__((ext_vector_type(2)));

__device__ __forceinline__ float bf2f(u16 u) {
    union { unsigned int i; float f; } v; v.i = ((unsigned int)u) << 16; return v.f;
}
__device__ __forceinline__ u16 f2bf(float f) {
    union { float f; unsigned int i; } v; v.f = f;
    unsigned int i = v.i;
    unsigned int r = i + 0x7fffu + ((i >> 16) & 1u);
    return (u16)(r >> 16);
}
__device__ __forceinline__ float asfloat(unsigned int u) {
    union { unsigned int i; float f; } v; v.i = u; return v.f;
}

// ---------------- x = concat(nfeats,names)*centrality, fused gap0 gate logit ----------------
__global__ __launch_bounds__(256) void k_init(const float* __restrict__ nf, const float* __restrict__ nm,
                                              const float* __restrict__ cent, const float* __restrict__ Wg,
                                              const float* __restrict__ bg,
                                              u16* __restrict__ x, float* __restrict__ g) {
    int node = blockIdx.x * 4 + (threadIdx.x >> 6);
    int lane = threadIdx.x & 63;
    float v = (lane < 48) ? nf[(size_t)node * 48 + lane] : nm[(size_t)node * 16 + lane - 48];
    float xf = v * cent[node];
    x[(size_t)node * 64 + lane] = f2bf(xf);
    float p = xf * Wg[lane];
#pragma unroll
    for (int mm = 1; mm < 64; mm <<= 1) p += __shfl_xor(p, mm);
    if (lane == 0) g[node] = p + bg[0];
}

// ---------------- pass 1: per-segment LDS bin sort by dst>>8 (block-local, write-merging) ----------------
__global__ __launch_bounds__(256) void k_bin1(const int* __restrict__ src, const int* __restrict__ dst,
                                              const float* __restrict__ ew,
                                              u32* __restrict__ bedge, u8* __restrict__ bdlo,
                                              int* __restrict__ runstart) {
    int s = blockIdx.x, t = threadIdx.x;
    int e0 = s * EPB;
    int n = N_EDGES - e0; if (n > EPB) n = EPB; if (n < 0) n = 0;
    __shared__ int lcnt[256];
    __shared__ int lcur[256];
    __shared__ int wsum[4];
    lcnt[t] = 0;
    __syncthreads();
    for (int i = t; i < n; i += 256) atomicAdd(&lcnt[dst[e0 + i] >> 8], 1);
    __syncthreads();
    int v = lcnt[t], orig = v;
    int lane = t & 63, w = t >> 6;
#pragma unroll
    for (int d = 1; d < 64; d <<= 1) {
        int u = __shfl_up(v, d);
        if (lane >= d) v += u;
    }
    if (lane == 63) wsum[w] = v;
    __syncthreads();
    int add = 0;
    for (int k = 0; k < w; k++) add += wsum[k];
    v += add;
    int excl = v - orig;
    if (t < SCAN_B) runstart[s * 197 + t] = excl;
    if (t == 255) runstart[s * 197 + 196] = v;     // segment count
    lcur[t] = excl;
    __syncthreads();
    for (int i = t; i < n; i += 256) {
        int d = dst[e0 + i];
        int pos = atomicAdd(&lcur[d >> 8], 1);
        bedge[e0 + pos] = ((u32)f2bf(ew[e0 + i]) << 16) | (u32)src[e0 + i];
        bdlo[e0 + pos] = (u8)(d & 255);
    }
}

// ---------------- pass 2a fused with scanA: per-bin node counts (LDS) -> block scan ----------------
__global__ __launch_bounds__(256) void k_cntscan(const int* __restrict__ runstart, const u8* __restrict__ bdlo,
                                                 int* __restrict__ rowptr, int* __restrict__ bsum) {
    int b = blockIdx.x, t = threadIdx.x;
    __shared__ int ndeg[256];
    __shared__ int wsum[4];
    ndeg[t] = 0;
    __syncthreads();
    for (int s = t; s < G1; s += 256) {
        int rs = runstart[s * 197 + b], re = runstart[s * 197 + b + 1];
        const u8* p = bdlo + (size_t)s * EPB;
        for (int i = rs; i < re; i++) atomicAdd(&ndeg[p[i]], 1);
    }
    __syncthreads();
    int v = ndeg[t], orig = v;
    int lane = t & 63, w = t >> 6;
#pragma unroll
    for (int d = 1; d < 64; d <<= 1) {
        int u = __shfl_up(v, d);
        if (lane >= d) v += u;
    }
    if (lane == 63) wsum[w] = v;
    __syncthreads();
    int add = 0;
    for (int k = 0; k < w; k++) add += wsum[k];
    v += add;
    int node = b * 256 + t;
    if (node < N_NODES) rowptr[node] = v - orig;   // local exclusive
    if (t == 255) bsum[b] = v;
}

// fused: block 0 = scan of block sums (+ rowptr[N]); blocks 1..12 = W transpose
__global__ __launch_bounds__(256) void k_scanBprep(const int* __restrict__ bsum, int* __restrict__ boff,
                                                   int* __restrict__ rowptr,
                                                   const float* __restrict__ W1, const float* __restrict__ W2,
                                                   const float* __restrict__ W3, u16* __restrict__ Wt) {
    __shared__ float tile[64][65];
    __shared__ int wsum[4];
    if (blockIdx.x == 0) {
        int t = threadIdx.x;
        int v = (t < SCAN_B) ? bsum[t] : 0;
        int orig = v;
        int lane = t & 63, w = t >> 6;
#pragma unroll
        for (int d = 1; d < 64; d <<= 1) {
            int u = __shfl_up(v, d);
            if (lane >= d) v += u;
        }
        if (lane == 63) wsum[w] = v;
        __syncthreads();
        int add = 0;
        for (int k = 0; k < w; k++) add += wsum[k];
        v += add;
        if (t < SCAN_B) boff[t] = v - orig;
        if (t == 0) rowptr[N_NODES] = N_EDGES;
        return;
    }
    int bb = blockIdx.x - 1;
    int l = bb >> 2, ti = bb & 3;
    const float* W = (l == 0) ? W1 : (l == 1) ? W2 : W3;
    u16* o = Wt + (size_t)l * 64 * 256;
    int t = threadIdx.x;
    for (int i = t; i < 64 * 64; i += 256) {
        int d = i >> 6, c = i & 63;
        tile[d][c] = W[d * 256 + ti * 64 + c];
    }
    __syncthreads();
    for (int i = t; i < 64 * 64; i += 256) {
        int c = i >> 6, d = i & 63;
        o[(size_t)(ti * 64 + c) * 64 + d] = f2bf(tile[d][c]);
    }
}

// ---------------- pass 2b: finalize rowptr + L2-local scatter of each bin into its CSR region ----------------
__global__ __launch_bounds__(256) void k_csr2(int* __restrict__ rowptr, const int* __restrict__ boff,
                                              const int* __restrict__ runstart, const u32* __restrict__ bedge,
                                              const u8* __restrict__ bdlo, u32* __restrict__ csr_se) {
    int b = blockIdx.x, t = threadIdx.x;
    __shared__ int cur[256];
    int node = b * 256 + t;
    if (node < N_NODES) {
        int val = rowptr[node] + boff[b];
        rowptr[node] = val;
        cur[t] = val;
    } else cur[t] = 0;
    __syncthreads();
    for (int s = t; s < G1; s += 256) {
        int rs = runstart[s * 197 + b], re = runstart[s * 197 + b + 1];
        const u32* pe = bedge + (size_t)s * EPB;
        const u8* pd = bdlo + (size_t)s * EPB;
        for (int i = rs; i < re; i++) {
            int pos = atomicAdd(&cur[pd[i]], 1);
            csr_se[pos] = pe[i];
        }
    }
}

// ---------------- GAP partial (device fn): 8 parts/graph, no-max exp ----------------
__device__ __forceinline__ void gap_part(int pb, const u16* __restrict__ x, const float* __restrict__ g,
                                         const int* __restrict__ gid,
                                         float* __restrict__ pnum, float* __restrict__ pden) {
    int part = pb & 7, b = pb >> 3;
    int t = threadIdx.x, w = t >> 6, lane = t & 63, q = lane >> 4, c = lane & 15;
    int lo = 0, hi = N_NODES;
    while (lo < hi) { int mid = (lo + hi) >> 1; if (gid[mid] < b) lo = mid + 1; else hi = mid; }
    int s = lo;
    lo = 0; hi = N_NODES;
    while (lo < hi) { int mid = (lo + hi) >> 1; if (gid[mid] < b + 1) lo = mid + 1; else hi = mid; }
    int e = lo;
    int len = e - s;
    int ps = s + (int)(((long long)len * part) >> 3);
    int pe = s + (int)(((long long)len * (part + 1)) >> 3);

    float a0 = 0.f, a1 = 0.f, a2 = 0.f, a3 = 0.f, den = 0.f;
    for (int n0 = ps + w * 4; n0 < pe; n0 += 16) {
        int node = n0 + q;
        if (node < pe) {
            float gate = __expf(fminf(g[node], 30.f));
            uint2 raw = *(const uint2*)(x + (size_t)node * 64 + c * 4);
            a0 = fmaf(gate, asfloat(raw.x << 16), a0);
            a1 = fmaf(gate, asfloat(raw.x & 0xffff0000u), a1);
            a2 = fmaf(gate, asfloat(raw.y << 16), a2);
            a3 = fmaf(gate, asfloat(raw.y & 0xffff0000u), a3);
            if (c == 0) den += gate;
        }
    }
#pragma unroll
    for (int mm = 16; mm < 64; mm <<= 1) {
        a0 += __shfl_xor(a0, mm); a1 += __shfl_xor(a1, mm);
        a2 += __shfl_xor(a2, mm); a3 += __shfl_xor(a3, mm);
        den += __shfl_xor(den, mm);
    }
    __shared__ float snum[4][64];
    __shared__ float sden[4];
    if (lane < 16) {
        snum[w][c * 4 + 0] = a0; snum[w][c * 4 + 1] = a1;
        snum[w][c * 4 + 2] = a2; snum[w][c * 4 + 3] = a3;
        if (lane == 0) sden[w] = den;
    }
    __syncthreads();
    if (t < 64) pnum[((size_t)b * 8 + part) * 64 + t] = snum[0][t] + snum[1][t] + snum[2][t] + snum[3][t];
    if (t == 0) pden[b * 8 + part] = sden[0] + sden[1] + sden[2] + sden[3];
}

// ---------------- fused: ft = X @ W (MFMA, fp8 output) + el/er  |  GAP partials ----------------
__global__ __launch_bounds__(256) void k_ftgap(const u16* __restrict__ X, const u16* __restrict__ Wt,
                                               const float* __restrict__ al, const float* __restrict__ ar,
                                               u8* __restrict__ ft, float* __restrict__ el, float* __restrict__ er,
                                               const float* __restrict__ g, const int* __restrict__ gid,
                                               float* __restrict__ pnum, float* __restrict__ pden) {
    if (blockIdx.x >= FT_B) {
        gap_part(blockIdx.x - FT_B, X, g, gid, pnum, pden);
        return;
    }
    int w = threadIdx.x >> 6;
    int lane = threadIdx.x & 63;
    int quad = lane >> 4, c = lane & 15;
    int n0 = blockIdx.x * 16;

    f32x4 acc[4];
#pragma unroll
    for (int t = 0; t < 4; t++) acc[t] = (f32x4){0.f, 0.f, 0.f, 0.f};

#pragma unroll
    for (int kh = 0; kh < 2; kh++) {
        s16x8 a = *(const s16x8*)(X + (size_t)(n0 + c) * 64 + kh * 32 + quad * 8);
#pragma unroll
        for (int t = 0; t < 4; t++) {
            int col = w * 64 + t * 16 + c;
            s16x8 b = *(const s16x8*)(Wt + (size_t)col * 64 + kh * 32 + quad * 8);
            acc[t] = __builtin_amdgcn_mfma_f32_16x16x32_bf16(a, b, acc[t], 0, 0, 0);
        }
    }

    __shared__ u8 sft[16 * 256];   // fp8 tile
    float alv[4], arv[4];
#pragma unroll
    for (int t = 0; t < 4; t++) {
        alv[t] = al[w * 64 + t * 16 + c];
        arv[t] = ar[w * 64 + t * 16 + c];
    }
    float pel[4] = {0.f, 0.f, 0.f, 0.f}, per[4] = {0.f, 0.f, 0.f, 0.f};
#pragma unroll
    for (int t = 0; t < 4; t++) {
#pragma unroll
        for (int r = 0; r < 4; r++) {
            float v = acc[t][r];
            int nl = quad * 4 + r;
            int d = t * 16 + c;
            int pk = __builtin_amdgcn_cvt_pk_fp8_f32(v, v, 0, false);
            sft[nl * 256 + d * 4 + w] = (u8)(pk & 0xff);
            pel[r] += v * alv[t];
            per[r] += v * arv[t];
        }
    }
#pragma unroll
    for (int r = 0; r < 4; r++) {
#pragma unroll
        for (int mm = 1; mm < 16; mm <<= 1) {
            pel[r] += __shfl_xor(pel[r], mm);
            per[r] += __shfl_xor(per[r], mm);
        }
    }
    if (c == 0) {
#pragma unroll
        for (int r = 0; r < 4; r++) {
            int node = n0 + quad * 4 + r;
            el[node * 4 + w] = pel[r];
            er[node * 4 + w] = per[r];
        }
    }
    __syncthreads();
    const uint4* s4 = (const uint4*)sft;
    uint4* g4 = (uint4*)(ft + (size_t)n0 * 256);
    g4[threadIdx.x] = s4[threadIdx.x];
}

// ---------------- per-dst-node edge softmax + aggregation (wave per node, fp8 gather) ----------------
__global__ __launch_bounds__(256) void k_agg(
    const u8* __restrict__ ft, const float4* __restrict__ el4, const float4* __restrict__ er4,
    const int* __restrict__ rowptr, const u32* __restrict__ csr_se,
    const float* __restrict__ bias, const float* __restrict__ Wg, const float* __restrict__ bg,
    u16* __restrict__ hout, float* __restrict__ gout) {
    int wv = threadIdx.x >> 6;
    int node = blockIdx.x * 4 + wv;
    int lane = threadIdx.x & 63;
    int beg = rowptr[node], end = rowptr[node + 1];
    float4 erv = er4[node];

    __shared__ int    s_off[4][64];
    __shared__ float4 s_p[4][64];

    float S0 = 0.f, S1 = 0.f, S2 = 0.f, S3 = 0.f;
    float a0 = 0.f, a1 = 0.f, a2 = 0.f, a3 = 0.f;

    const char* ftl = (const char*)ft + lane * 4;

    for (int base = beg; base < end; base += 64) {
        int cnt = end - base; if (cnt > 64) cnt = 64;
        if (lane < cnt) {
            u32 se = csr_se[base + lane];
            int sidx = (int)(se & 0xffffu);
            float w = bf2f((u16)(se >> 16));
            float4 elv = el4[sidx];
            float t0 = elv.x + erv.x, t1 = elv.y + erv.y, t2 = elv.z + erv.z, t3 = elv.w + erv.w;
            t0 = t0 > 0.f ? t0 : 0.2f * t0;
            t1 = t1 > 0.f ? t1 : 0.2f * t1;
            t2 = t2 > 0.f ? t2 : 0.2f * t2;
            t3 = t3 > 0.f ? t3 : 0.2f * t3;
            float p0 = __expf(fminf(t0, 30.f));
            float p1 = __expf(fminf(t1, 30.f));
            float p2 = __expf(fminf(t2, 30.f));
            float p3 = __expf(fminf(t3, 30.f));
            S0 += p0; S1 += p1; S2 += p2; S3 += p3;
            s_off[wv][lane] = sidx * 256;
            s_p[wv][lane] = make_float4(p0 * w, p1 * w, p2 * w, p3 * w);
        }
        int k = 0;
        for (; k + 4 <= cnt; k += 4) {
            int o0 = s_off[wv][k], o1 = s_off[wv][k + 1], o2 = s_off[wv][k + 2], o3 = s_off[wv][k + 3];
            unsigned r0 = *(const unsigned*)(ftl + o0);
            unsigned r1 = *(const unsigned*)(ftl + o1);
            unsigned r2 = *(const unsigned*)(ftl + o2);
            unsigned r3 = *(const unsigned*)(ftl + o3);
            float4 q0 = s_p[wv][k], q1 = s_p[wv][k + 1], q2 = s_p[wv][k + 2], q3 = s_p[wv][k + 3];
            f32x2 l0 = __builtin_amdgcn_cvt_pk_f32_fp8(r0, false), h0 = __builtin_amdgcn_cvt_pk_f32_fp8(r0, true);
            f32x2 l1 = __builtin_amdgcn_cvt_pk_f32_fp8(r1, false), h1 = __builtin_amdgcn_cvt_pk_f32_fp8(r1, true);
            f32x2 l2 = __builtin_amdgcn_cvt_pk_f32_fp8(r2, false), h2 = __builtin_amdgcn_cvt_pk_f32_fp8(r2, true);
            f32x2 l3 = __builtin_amdgcn_cvt_pk_f32_fp8(r3, false), h3 = __builtin_amdgcn_cvt_pk_f32_fp8(r3, true);
            a0 = fmaf(q0.x, l0.x, a0); a1 = fmaf(q0.y, l0.y, a1);
            a2 = fmaf(q0.z, h0.x, a2); a3 = fmaf(q0.w, h0.y, a3);
            a0 = fmaf(q1.x, l1.x, a0); a1 = fmaf(q1.y, l1.y, a1);
            a2 = fmaf(q1.z, h1.x, a2); a3 = fmaf(q1.w, h1.y, a3);
            a0 = fmaf(q2.x, l2.x, a0); a1 = fmaf(q2.y, l2.y, a1);
            a2 = fmaf(q2.z, h2.x, a2); a3 = fmaf(q2.w, h2.y, a3);
            a0 = fmaf(q3.x, l3.x, a0); a1 = fmaf(q3.y, l3.y, a1);
            a2 = fmaf(q3.z, h3.x, a2); a3 = fmaf(q3.w, h3.y, a3);
        }
        for (; k < cnt; k++) {
            int o0 = s_off[wv][k];
            float4 q0 = s_p[wv][k];
            unsigned r0 = *(const unsigned*)(ftl + o0);
            f32x2 l0 = __builtin_amdgcn_cvt_pk_f32_fp8(r0, false), h0 = __builtin_amdgcn_cvt_pk_f32_fp8(r0, true);
            a0 = fmaf(q0.x, l0.x, a0); a1 = fmaf(q0.y, l0.y, a1);
            a2 = fmaf(q0.z, h0.x, a2); a3 = fmaf(q0.w, h0.y, a3);
        }
    }
#pragma unroll
    for (int mm = 1; mm < 64; mm <<= 1) {
        S0 += __shfl_xor(S0, mm);
        S1 += __shfl_xor(S1, mm);
        S2 += __shfl_xor(S2, mm);
        S3 += __shfl_xor(S3, mm);
    }
    float i0 = S0 > 0.f ? 1.f / S0 : 0.f;
    float i1 = S1 > 0.f ? 1.f / S1 : 0.f;
    float i2 = S2 > 0.f ? 1.f / S2 : 0.f;
    float i3 = S3 > 0.f ? 1.f / S3 : 0.f;
    float r0 = a0 * i0 + bias[lane];
    float r1 = a1 * i1 + bias[64 + lane];
    float r2 = a2 * i2 + bias[128 + lane];
    float r3 = a3 * i3 + bias[192 + lane];
    float o = (fmaxf(r0, 0.f) + fmaxf(r1, 0.f) + fmaxf(r2, 0.f) + fmaxf(r3, 0.f)) * 0.25f;
    hout[(size_t)node * 64 + lane] = f2bf(o);
    float pg = o * Wg[lane];
#pragma unroll
    for (int mm = 1; mm < 64; mm <<= 1) pg += __shfl_xor(pg, mm);
    if (lane == 0) gout[node] = pg + bg[0];
}

// ---------------- standalone GAP (final layer) ----------------
__global__ __launch_bounds__(256) void k_gapP(const u16* __restrict__ x, const float* __restrict__ g,
                                              const int* __restrict__ gid,
                                              float* __restrict__ pnum, float* __restrict__ pden) {
    gap_part(blockIdx.x, x, g, gid, pnum, pden);
}

// ---------------- LSTM (4 steps) + final linear + sigmoid; combines gap partials ----------------
__global__ __launch_bounds__(256) void k_lstm(const float* __restrict__ pnum, const float* __restrict__ pden,
                                              const float* __restrict__ Wih, const float* __restrict__ Whh,
                                              const float* __restrict__ bih, const float* __restrict__ bhh,
                                              const float* __restrict__ Wc, const float* __restrict__ bc,
                                              float* __restrict__ out) {
    int b = blockIdx.x, t = threadIdx.x;
    __shared__ float h[64], c[64], G[256], xv[64], red[64];
    if (t < 64) { h[t] = 0.f; c[t] = 0.f; }
    __syncthreads();
    for (int step = 0; step < 4; step++) {
        if (t < 64) {
            const float* pn = pnum + (((size_t)step * N_GRAPHS + b) * 8) * 64;
            const float* pd = pden + ((size_t)step * N_GRAPHS + b) * 8;
            float num = 0.f, dn = 0.f;
#pragma unroll
            for (int pp = 0; pp < 8; pp++) { num += pn[pp * 64 + t]; dn += pd[pp]; }
            xv[t] = (dn > 0.f) ? num / dn : 0.f;
        }
        __syncthreads();
        float acc = bih[t] + bhh[t];
#pragma unroll 4
        for (int d = 0; d < 64; d++)
            acc += xv[d] * Wih[t * 64 + d] + h[d] * Whh[t * 64 + d];
        G[t] = acc;
        __syncthreads();
        if (t < 64) {
            float ig = 1.f / (1.f + __expf(-G[t]));
            float fg = 1.f / (1.f + __expf(-G[64 + t]));
            float gg = tanhf(G[128 + t]);
            float og = 1.f / (1.f + __expf(-G[192 + t]));
            float cn = fg * c[t] + ig * gg;
            c[t] = cn;
            h[t] = og * tanhf(cn);
        }
        __syncthreads();
    }
    if (t < 64) red[t] = h[t] * Wc[t];
    __syncthreads();
    if (t == 0) {
        float r = 0.f;
        for (int i = 0; i < 64; i++) r += red[i];
        r += bc[0];
        out[b] = 1.f / (1.f + __expf(-r));
    }
}

extern "C" void kernel_launch(void* const* d_in, const int* in_sizes, int n_in,
                              void* d_out, int out_size, void* d_ws, size_t ws_size,
                              hipStream_t stream) {
    const float* nf   = (const float*)d_in[0];
    const float* nm   = (const float*)d_in[1];
    const float* cent = (const float*)d_in[2];
    const float* ew   = (const float*)d_in[3];
    const int* src  = (const int*)d_in[4];
    const int* dst  = (const int*)d_in[5];
    const int* gid  = (const int*)d_in[6];
    const float* W[3]  = {(const float*)d_in[7],  (const float*)d_in[11], (const float*)d_in[15]};
    const float* al[3] = {(const float*)d_in[8],  (const float*)d_in[12], (const float*)d_in[16]};
    const float* ar[3] = {(const float*)d_in[9],  (const float*)d_in[13], (const float*)d_in[17]};
    const float* bb[3] = {(const float*)d_in[10], (const float*)d_in[14], (const float*)d_in[18]};
    const float* Wg[4] = {(const float*)d_in[19], (const float*)d_in[21], (const float*)d_in[23], (const float*)d_in[25]};
    const float* bg[4] = {(const float*)d_in[20], (const float*)d_in[22], (const float*)d_in[24], (const float*)d_in[26]};
    const float* Wih = (const float*)d_in[27];
    const float* Whh = (const float*)d_in[28];
    const float* bih = (const float*)d_in[29];
    const float* bhh = (const float*)d_in[30];
    const float* Wc  = (const float*)d_in[31];
    const float* bc  = (const float*)d_in[32];
    float* out = (float*)d_out;

    char* p = (char*)d_ws;
    size_t off = 0;
    auto A = [&](size_t bytes) -> char* {
        char* r = p + off;
        off += (bytes + 255) & ~(size_t)255;
        return r;
    };
    u8*    ftb     = (u8*)   A((size_t)N_NODES * 256);       // 12.8 MB fp8
    u16*   nodebuf = (u16*)  A((size_t)N_NODES * 64 * 2);    // 6.4 MB
    u32*   csr_se  = (u32*)  A((size_t)N_EDGES * 4);         // 3.2 MB packed (ew_bf16 | src_u16)
    u32*   bedge   = (u32*)  A((size_t)G1 * EPB * 4);        // 3.2 MB segment-binned edges
    u8*    bdlo    = (u8*)   A((size_t)G1 * EPB);            // 0.8 MB dst low byte
    int*   runstart= (int*)  A((size_t)G1 * 197 * 4);        // 0.6 MB
    float* el      = (float*)A((size_t)N_NODES * 4 * 4);
    float* er      = (float*)A((size_t)N_NODES * 4 * 4);
    float* gbuf    = (float*)A((size_t)N_NODES * 4);
    int*   rowptr  = (int*)  A((size_t)(N_NODES + 1) * 4);
    float* pnum    = (float*)A((size_t)4 * N_GRAPHS * 8 * 64 * 4);
    float* pden    = (float*)A((size_t)4 * N_GRAPHS * 8 * 4);
    int*   bsum    = (int*)  A((size_t)SCAN_B * 4);
    int*   boff    = (int*)  A((size_t)SCAN_B * 4);
    u16*   Wt      = (u16*)  A((size_t)3 * 64 * 256 * 2);

    k_init<<<N_NODES / 4, 256, 0, stream>>>(nf, nm, cent, Wg[0], bg[0], nodebuf, gbuf);
    k_bin1<<<G1, 256, 0, stream>>>(src, dst, ew, bedge, bdlo, runstart);
    k_cntscan<<<SCAN_B, 256, 0, stream>>>(runstart, bdlo, rowptr, bsum);
    k_scanBprep<<<13, 256, 0, stream>>>(bsum, boff, rowptr, W[0], W[1], W[2], Wt);
    k_csr2<<<SCAN_B, 256, 0, stream>>>(rowptr, boff, runstart, bedge, bdlo, csr_se);

    for (int l = 0; l < 3; l++) {
        k_ftgap<<<FT_B + GAP_B, 256, 0, stream>>>(nodebuf, Wt + (size_t)l * 64 * 256, al[l], ar[l],
                                                  ftb, el, er, gbuf, gid,
                                                  pnum + (size_t)l * N_GRAPHS * 8 * 64,
                                                  pden + (size_t)l * N_GRAPHS * 8);
        k_agg<<<N_NODES / 4, 256, 0, stream>>>(ftb, (const float4*)el, (const float4*)er, rowptr,
                                               csr_se, bb[l], Wg[l + 1], bg[l + 1], nodebuf, gbuf);
    }
    k_gapP<<<GAP_B, 256, 0, stream>>>(nodebuf, gbuf, gid,
                                      pnum + (size_t)3 * N_GRAPHS * 8 * 64,
                                      pden + (size_t)3 * N_GRAPHS * 8);
    k_lstm<<<N_GRAPHS, 256, 0, stream>>>(pnum, pden, Wih, Whh, bih, bhh, Wc, bc, out);
}